// Round 15
// baseline (190.862 us; speedup 1.0000x reference)
//
#include <hip/hip_runtime.h>
#include <cstddef>
#include <cstdint>

#define DIM   256
#define KCODE 8192
#define NTOK  16384
#define NCBG  8          // phase1 code groups of 1024
#define HMARGIN 0.25f    // phase1 works in half-units (0.5*wn - dot)
#define UFLAG 0x40000000

typedef __attribute__((ext_vector_type(8))) short short8;
typedef __attribute__((ext_vector_type(8))) unsigned short ushort8;
typedef __attribute__((ext_vector_type(4))) unsigned short ushort4v;
typedef __attribute__((ext_vector_type(4))) float floatx4;

__device__ __forceinline__ unsigned short f2bf(float f) {  // RNE float->bf16
  uint32_t u = __builtin_bit_cast(uint32_t, f);
  return (unsigned short)((u + 0x7fffu + ((u >> 16) & 1u)) >> 16);
}
__device__ __forceinline__ float bf2f(unsigned short h) {
  return __builtin_bit_cast(float, (uint32_t)h << 16);
}

typedef const __attribute__((address_space(1))) unsigned int guint_t;
typedef __attribute__((address_space(3))) unsigned int luint_t;
__device__ __forceinline__ void gload_lds16(const void* g, void* l) {
  __builtin_amdgcn_global_load_lds((guint_t*)g, (luint_t*)l, 16, 0, 0);
}

// ---- TILED w0/w1 global layout (verified bit-exact since R3) ----
// tile t = 32 codebook rows (16 KB). Region (kc,h) = 1024 B at (kc*2+h)*1024.
// Slot s = quad*16 + (l15^kc) (16 B) holds chunk (row h*16+l15, 16B-col kc*4+quad).
// A wave DMA of one region (base + lane*16) is contiguous 1024 B in global AND
// lands as the conflict-free k-major LDS image (reads: lane*16 ^ kc<<4).

// ---- kernel 1: bf16 split convert (x negated, w two-word TILED) + w norms ----
__global__ __launch_bounds__(256) void prep_kernel(const float* __restrict__ x,
    const float* __restrict__ w, unsigned short* __restrict__ x0n,
    unsigned short* __restrict__ w0, unsigned short* __restrict__ w1,
    float* __restrict__ wn2, float* __restrict__ wnf, int* __restrict__ ucount) {
  if (blockIdx.x == 0 && threadIdx.x == 0) *ucount = 0;
  const int lane = threadIdx.x & 63, wv = threadIdx.x >> 6;
  const int l32 = lane & 31;
  const int row = blockIdx.x * 8 + wv * 2 + (lane >> 5);
  const bool is_x = row < NTOK;
  const float* src = is_x ? (x + (size_t)row * DIM) : (w + (size_t)(row - NTOK) * DIM);
  const float4 f0 = ((const float4*)src)[l32 * 2];
  const float4 f1 = ((const float4*)src)[l32 * 2 + 1];
  const float f[8] = {f0.x, f0.y, f0.z, f0.w, f1.x, f1.y, f1.z, f1.w};
  if (is_x) {  // store bf16(-x): MFMA then accumulates (norm - dot) directly
    ushort8 o;
#pragma unroll
    for (int i = 0; i < 8; ++i) o[i] = f2bf(-f[i]);
    *(ushort8*)(x0n + (size_t)row * DIM + l32 * 8) = o;
  } else {     // two-word split: w = w0 + w1 (+ ~2^-17 residual), TILED store
    ushort8 h8, l8;
#pragma unroll
    for (int i = 0; i < 8; ++i) {
      h8[i] = f2bf(f[i]);
      l8[i] = f2bf(f[i] - bf2f(h8[i]));
    }
    const int wr = row - NTOK;
    const int kc = l32 >> 2, quad = l32 & 3;
    const size_t off = (size_t)(wr >> 5) * 8192                      // tile (shorts)
                     + (size_t)(kc * 2 + ((wr >> 4) & 1)) * 512      // region
                     + (size_t)(quad * 16 + ((wr & 15) ^ kc)) * 8;   // slot
    *(ushort8*)(w0 + off) = h8;
    *(ushort8*)(w1 + off) = l8;
    float s = f[0]*f[0] + f[1]*f[1] + f[2]*f[2] + f[3]*f[3] +
              f[4]*f[4] + f[5]*f[5] + f[6]*f[6] + f[7]*f[7];
#pragma unroll
    for (int off2 = 1; off2 < 32; off2 <<= 1) s += __shfl_xor(s, off2);
    if (l32 == 0) { wn2[wr] = 0.5f * s; wnf[wr] = s; }
  }
}

// ---- kernel 2: phase1 bf16 screen. 8 waves x 32 tok = 256 tok/block. ----
// R8/R12 wave code (proven: VGPR=84, conflicts=0, no spill) at DOUBLED block
// width: 512 threads, grid 512, 2 blocks/CU = 4 waves/SIMD. When one block's
// waves sit in the barrier drain, the other block has 2 waves/SIMD to fill
// (vs 1 at R12's 4-wave blocks) — fill capacity was the measured residual
// (~2600 cyc wait/sub vs ~500 cyc work). Also halves L2 staging traffic
// (each 16KB tile now feeds 256 tokens) and per-token barrier count.
// vmcnt: 2 DMA loads/wave/tile (16 regions / 8 waves) -> steady outstanding =
// tile s(2) + tile s+1(2) + wn(2) = 6, WAIT(4) forces tile s complete.
__global__ __launch_bounds__(512) __attribute__((amdgpu_waves_per_eu(2, 8)))
void phase1_kernel(
    const unsigned short* __restrict__ x0n, const unsigned short* __restrict__ w0,
    const float* __restrict__ wn2,
    float* __restrict__ pv1, int* __restrict__ pc1, float* __restrict__ pv2) {
  __shared__ char smem[49152];  // ring 3 x 16KB
  const int tid = threadIdx.x;
  const int tb = blockIdx.x >> 3;    // 0..63 (256 tokens)
  const int cbg = blockIdx.x & 7;    // blockIdx%8 = XCD -> 512KB w0 slice per XCD L2
  const int lane = tid & 63, wv = tid >> 6;   // wv in 0..7
  const int l15 = lane & 15, quad = lane >> 4;
  const int lane16 = lane << 4;

  // resident A FIRST in vmcnt FIFO: wave wv owns 32 tokens; af[2][8] = 64 VGPRs
  short8 af[2][8];
#pragma unroll
  for (int mt = 0; mt < 2; ++mt) {
    const unsigned short* xr =
        x0n + (size_t)(tb * 256 + wv * 32 + mt * 16 + l15) * DIM + quad * 8;
#pragma unroll
    for (int kc = 0; kc < 8; ++kc) af[mt][kc] = *(const short8*)(xr + kc * 32);
  }

  // DMA sources: wave wv stages regions wv*2, wv*2+1; contiguous 1024B each.
  const char* wb = (const char*)w0 + (size_t)cbg * 32 * 16384;  // 512KB slice
  const char* g0 = wb + (wv * 2 + 0) * 1024 + lane16;
  const char* g1 = wb + (wv * 2 + 1) * 1024 + lane16;

  float bv1[8], bv2[8];
  int bc1[8];
#pragma unroll
  for (int i = 0; i < 8; ++i) { bv1[i] = -3.4e38f; bv2[i] = -3.4e38f; bc1[i] = 0; }

#define P1_DMA(BUFOFF) { \
    gload_lds16(g0, smem + (BUFOFF) + (wv * 2 + 0) * 1024); \
    gload_lds16(g1, smem + (BUFOFF) + (wv * 2 + 1) * 1024); \
    g0 += 16384; g1 += 16384; }

// counted wait: tile s landed; barrier: all waves' portions landed AND all
// waves are past compute(s-1); fence: nothing sinks/hoists across.
#define P1_WAIT(N) \
    asm volatile("s_waitcnt vmcnt(" #N ")" ::: "memory"); \
    __builtin_amdgcn_s_barrier(); \
    asm volatile("" ::: "memory");

#define P1_COMPUTE(BUF, LOADN) { \
    const float cw0 = nw0, cw1 = nw1; \
    wnp += 32; \
    if (LOADN) { nw0 = wnp[0]; nw1 = wnp[16]; } \
    floatx4 acc[2][2]; \
    _Pragma("unroll") \
    for (int mt = 0; mt < 2; ++mt) { \
      acc[mt][0] = (floatx4){cw0, cw0, cw0, cw0}; \
      acc[mt][1] = (floatx4){cw1, cw1, cw1, cw1}; \
    } \
    _Pragma("unroll") \
    for (int kc = 0; kc < 8; ++kc) { \
      const int ra = lane16 ^ (kc << 4); \
      const short8 b0 = *(const short8*)(smem + (BUF) + kc * 2048 + ra); \
      const short8 b1 = *(const short8*)(smem + (BUF) + kc * 2048 + 1024 + ra); \
      _Pragma("unroll") \
      for (int mt = 0; mt < 2; ++mt) { \
        acc[mt][0] = __builtin_amdgcn_mfma_f32_16x16x32_bf16(af[mt][kc], b0, acc[mt][0], 0, 0, 0); \
        acc[mt][1] = __builtin_amdgcn_mfma_f32_16x16x32_bf16(af[mt][kc], b1, acc[mt][1], 0, 0, 0); \
      } \
    } \
    _Pragma("unroll") \
    for (int mt = 0; mt < 2; ++mt) { \
      _Pragma("unroll") \
      for (int reg = 0; reg < 4; ++reg) { \
        const int cell = mt * 4 + reg; \
        const float c0 = acc[mt][0][reg], c1 = acc[mt][1][reg]; \
        const float hi = fmaxf(c0, c1), lo = fminf(c0, c1); \
        const int ch = (c1 > c0) ? (code0 + 16) : code0;  /* tie -> lower code */ \
        const float t = fminf(bv1[cell], hi); \
        bc1[cell] = (hi > bv1[cell]) ? ch : bc1[cell];    /* tie -> earlier */ \
        bv1[cell] = fmaxf(bv1[cell], hi); \
        bv2[cell] = fmaxf(fmaxf(bv2[cell], t), lo);       /* v_max3_f32 */ \
      } \
    } \
    code0 += 32; }

  P1_DMA(0)       // tile 0 -> buf0
  P1_DMA(16384)   // tile 1 -> buf1
  const float* wnp = wn2 + cbg * 1024 + l15;
  float nw0 = wnp[0], nw1 = wnp[16];   // wn(0): 2 VMEM, newest in FIFO
  int code0 = cbg * 1024 + l15;

  // subs 0..29 (uniform: WAIT(4), issue tile s+2, compute s), 3-unrolled.
#pragma unroll 1
  for (int s3 = 0; s3 < 10; ++s3) {
    P1_WAIT(4) P1_DMA(32768) P1_COMPUTE(0, 1)       // s=3k:   buf0, issue->buf2
    P1_WAIT(4) P1_DMA(0)     P1_COMPUTE(16384, 1)   // s=3k+1: buf1, issue->buf0
    P1_WAIT(4) P1_DMA(16384) P1_COMPUTE(32768, 1)   // s=3k+2: buf2, issue->buf1
  }
  P1_WAIT(4) P1_COMPUTE(0, 1)       // s=30: buf0 (tile 30), prefetch wn(31)
  P1_WAIT(2) P1_COMPUTE(16384, 0)   // s=31: buf1 (tile 31); wn(31) is newest 2
#undef P1_DMA
#undef P1_WAIT
#undef P1_COMPUTE

  // epilogue: the 16 per-token candidates live in lanes quad*16+l15 of THIS
  // wave -> 16-lane xor-butterfly top-2 merge, no LDS, no barriers.
  // Ties: V2 ends == V1 -> gap 0 -> rescore; lane 0 keeps lowest tying code.
#pragma unroll
  for (int mt = 0; mt < 2; ++mt)
#pragma unroll
    for (int reg = 0; reg < 4; ++reg) {
      const int cell = mt * 4 + reg;
      float V1 = bv1[cell], V2 = bv2[cell];
      int C1 = bc1[cell];
#pragma unroll
      for (int off = 1; off < 16; off <<= 1) {
        const float ov1 = __shfl_xor(V1, off);
        const float ov2 = __shfl_xor(V2, off);
        const int   oc1 = __shfl_xor(C1, off);
        const bool take = ov1 > V1;
        V2 = fmaxf(fminf(V1, ov1), take ? ov2 : V2);
        V1 = take ? ov1 : V1;
        C1 = take ? oc1 : C1;
      }
      if (l15 == 0) {
        const int tok = wv * 32 + mt * 16 + quad * 4 + reg;  // C/D: row=quad*4+reg
        const size_t o = (size_t)cbg * NTOK + tb * 256 + tok;
        pv1[o] = V1; pc1[o] = C1; pv2[o] = V2;
      }
    }
}

// ---- kernel 3: FUSED merge + uncertain-compact-gather ----
// Per block: merge 8 group partials for 256 tokens; uncertain tokens get a
// global slot p (atomicAdd) and are recorded in LDS; then the block's 4 waves
// cooperatively write the compact two-word rows (same math as old xgather,
// bit-exact). Pad rows [uc, ucp) are NOT zeroed: rescore's s<uc guard discards
// every output that could depend on them.
__global__ __launch_bounds__(256) void reduce_kernel(
    const float* __restrict__ pv1, const int* __restrict__ pc1,
    const float* __restrict__ pv2, const float* __restrict__ x,
    const unsigned short* __restrict__ x0n, int* __restrict__ final_idx,
    int* __restrict__ ucount, unsigned short* __restrict__ xgh,
    unsigned short* __restrict__ xgl) {
  __shared__ int ltok[256], lslot[256];
  __shared__ int lcnt;
  const int tid = threadIdx.x;
  if (tid == 0) lcnt = 0;
  __syncthreads();
  const int n = blockIdx.x * 256 + tid;
  float V1 = -3.4e38f, V2 = -3.4e38f;
  int C1 = 0;
#pragma unroll
  for (int cb = 0; cb < NCBG; ++cb) {
    const size_t o = (size_t)cb * NTOK + n;
    const float v1 = pv1[o], v2 = pv2[o];
    const int c1 = pc1[o];
    if (v1 > V1) { V2 = fmaxf(V1, v2); V1 = v1; C1 = c1; }
    else V2 = fmaxf(V2, v1);
  }
  if (V1 - V2 < HMARGIN) {
    const int p = atomicAdd(ucount, 1);
    const int li = atomicAdd(&lcnt, 1);
    ltok[li] = n; lslot[li] = p;
    final_idx[n] = UFLAG | p;   // gather resolves via p2 slot p
  } else {
    final_idx[n] = C1;
  }
  __syncthreads();
  const int cnt = lcnt;
  const int wv = tid >> 6, lane = tid & 63;
  for (int i = wv; i < cnt; i += 4) {   // wave-per-uncertain-row
    const int tok = ltok[i], s = lslot[i];
    const ushort4v h = ((const ushort4v*)(x0n + (size_t)tok * DIM))[lane];
    const float4 f = ((const float4*)(x + (size_t)tok * DIM))[lane];
    ushort4v l;
    l[0] = f2bf(-f.x - bf2f(h[0]));
    l[1] = f2bf(-f.y - bf2f(h[1]));
    l[2] = f2bf(-f.z - bf2f(h[2]));
    l[3] = f2bf(-f.w - bf2f(h[3]));
    ((ushort4v*)(xgh + (size_t)s * DIM))[lane] = h;
    ((ushort4v*)(xgl + (size_t)s * DIM))[lane] = l;
  }
}

// ---- kernel 5: rescore v2 -- 128 slots/block, LDS-staged B (4x dedup) ----
// block = 4 waves x 32 slots = 128 slots; slice = 256 codes; grid 32x32.
// Per sub (32 codes): stage w0-tile + w1-tile (32KB) ONCE via global_load_lds
// (tiled layout: contiguous regions, conflict-free lane16^kc reads), all 4
// waves consume it -> per-slot B L2-traffic drops 4x vs R11. 2x32KB dbuf,
// one __syncthreads per sub (128 MFMA hides the DMA; R7-proven scheme).
// NO setprio (R13: negative on lockstep structures).
// Epilogue: codes live in l15 lanes of the owning wave -> in-wave 16-lane
// butterfly (max v, tie -> lower code; same total order as R11), no LDS.
// Per-(slot,code) FMA chain order identical to R11 -> bit-exact outputs.
__global__ __launch_bounds__(256) __attribute__((amdgpu_waves_per_eu(2, 8)))
void rescore_kernel(
    const unsigned short* __restrict__ xgh, const unsigned short* __restrict__ xgl,
    const unsigned short* __restrict__ w0, const unsigned short* __restrict__ w1,
    const float* __restrict__ wnf, const int* __restrict__ ucount,
    float* __restrict__ p2v, int* __restrict__ p2c) {
  const int uc = *ucount;
  if (uc == 0) return;
  const int ucp = (uc + 127) & ~127;
  const int sl = blockIdx.x & 31, g0 = blockIdx.x >> 5;  // g0 in [0,32)
  __shared__ char smem[65536];  // 2 x (w0-tile 16K | w1-tile 16K)
  const int tid = threadIdx.x;
  const int lane = tid & 63, wv = tid >> 6;
  const int l15 = lane & 15, quad = lane >> 4;
  const int lane16 = lane << 4;

  // DMA geometry: wave wv stages regions wv*8+j (j<8) of the 32KB sub-buffer:
  // wv 0,1 -> w0 tile regions 0-7 / 8-15; wv 2,3 -> w1 tile same. Source is
  // contiguous (tiled layout); dst is wave-uniform (gload_lds adds lane*16).
  const char* wsel = (wv < 2) ? (const char*)w0 : (const char*)w1;
  const char* wbase = wsel + (size_t)sl * 8 * 16384 + (size_t)(wv & 1) * 8192 + lane16;
  const int dstb = wv * 8192;

#define RS_DMA(BUF, SUB) { \
    _Pragma("unroll") \
    for (int j = 0; j < 8; ++j) \
      gload_lds16(wbase + (size_t)(SUB) * 16384 + j * 1024, \
                  smem + (BUF) + dstb + j * 1024); }

  for (int g = g0; g * 128 < ucp; g += 32) {
    RS_DMA(0, 0)   // sub 0 -> buf0 (lands under the A-loads below)

    short8 ah[2][8], al[2][8];  // 128 VGPRs
#pragma unroll
    for (int mt = 0; mt < 2; ++mt) {
      const size_t rb = (size_t)(g * 128 + wv * 32 + mt * 16 + l15) * DIM + quad * 8;
#pragma unroll
      for (int kc = 0; kc < 8; ++kc) {
        ah[mt][kc] = *(const short8*)(xgh + rb + kc * 32);
        al[mt][kc] = *(const short8*)(xgl + rb + kc * 32);
      }
    }
    float bv[8];
    int bc[8];
#pragma unroll
    for (int i = 0; i < 8; ++i) { bv[i] = -3.4e38f; bc[i] = 0; }

    const float* wnp = wnf + sl * 256 + l15;
    int code0 = sl * 256 + l15;
    __syncthreads();   // sub 0 landed (compiler drains vmcnt at barrier)

#pragma unroll 1
    for (int sub = 0; sub < 8; ++sub) {
      const int buf = (sub & 1) * 32768;
      if (sub < 7) RS_DMA((buf ^ 32768), sub + 1)
      floatx4 acc[2][2];
#pragma unroll
      for (int mt = 0; mt < 2; ++mt)
#pragma unroll
        for (int h = 0; h < 2; ++h) acc[mt][h] = (floatx4){0.f, 0.f, 0.f, 0.f};
#pragma unroll
      for (int kc = 0; kc < 8; ++kc) {
        const int ra = lane16 ^ (kc << 4);
        const short8 bh0 = *(const short8*)(smem + buf + kc * 2048 + ra);
        const short8 bh1 = *(const short8*)(smem + buf + kc * 2048 + 1024 + ra);
        const short8 bl0 = *(const short8*)(smem + buf + 16384 + kc * 2048 + ra);
        const short8 bl1 = *(const short8*)(smem + buf + 16384 + kc * 2048 + 1024 + ra);
#pragma unroll
        for (int mt = 0; mt < 2; ++mt) {
          acc[mt][0] = __builtin_amdgcn_mfma_f32_16x16x32_bf16(al[mt][kc], bl0, acc[mt][0], 0, 0, 0);
          acc[mt][0] = __builtin_amdgcn_mfma_f32_16x16x32_bf16(ah[mt][kc], bl0, acc[mt][0], 0, 0, 0);
          acc[mt][0] = __builtin_amdgcn_mfma_f32_16x16x32_bf16(al[mt][kc], bh0, acc[mt][0], 0, 0, 0);
          acc[mt][0] = __builtin_amdgcn_mfma_f32_16x16x32_bf16(ah[mt][kc], bh0, acc[mt][0], 0, 0, 0);
          acc[mt][1] = __builtin_amdgcn_mfma_f32_16x16x32_bf16(al[mt][kc], bl1, acc[mt][1], 0, 0, 0);
          acc[mt][1] = __builtin_amdgcn_mfma_f32_16x16x32_bf16(ah[mt][kc], bl1, acc[mt][1], 0, 0, 0);
          acc[mt][1] = __builtin_amdgcn_mfma_f32_16x16x32_bf16(al[mt][kc], bh1, acc[mt][1], 0, 0, 0);
          acc[mt][1] = __builtin_amdgcn_mfma_f32_16x16x32_bf16(ah[mt][kc], bh1, acc[mt][1], 0, 0, 0);
        }
      }
      const float wn0 = wnp[0], wn1 = wnp[16];
      // acc = -(x.w); dist = wn + 2*acc
#pragma unroll
      for (int mt = 0; mt < 2; ++mt) {
#pragma unroll
        for (int reg = 0; reg < 4; ++reg) {
          const int cell = mt * 4 + reg;
          const float d0 = fmaf(2.0f, acc[mt][0][reg], wn0);
          const float d1 = fmaf(2.0f, acc[mt][1][reg], wn1);
          const float hi = fmaxf(d0, d1);
          const int ch = (d1 > d0) ? (code0 + 16) : code0;  // tie -> lower code
          bc[cell] = (hi > bv[cell]) ? ch : bc[cell];
          bv[cell] = fmaxf(bv[cell], hi);
        }
      }
      wnp += 32;
      code0 += 32;
      __syncthreads();   // sub+1 landed; all readers of buf done
    }

    // epilogue: in-wave butterfly over the 16 code-lanes (same total order:
    // max v, tie -> lower code). Slot = wv*32 + mt*16 + quad*4 + reg.
#pragma unroll
    for (int mt = 0; mt < 2; ++mt)
#pragma unroll
      for (int reg = 0; reg < 4; ++reg) {
        const int cell = mt * 4 + reg;
        float V = bv[cell];
        int C = bc[cell];
#pragma unroll
        for (int off = 1; off < 16; off <<= 1) {
          const float ov = __shfl_xor(V, off);
          const int oc = __shfl_xor(C, off);
          if (ov > V || (ov == V && oc < C)) { V = ov; C = oc; }
        }
        if (l15 == 0) {
          const int s = g * 128 + wv * 32 + mt * 16 + quad * 4 + reg;
          if (s < uc) {
            p2v[(size_t)sl * NTOK + s] = V;
            p2c[(size_t)sl * NTOK + s] = C;
          }
        }
      }
  }
#undef RS_DMA
}

// ---- kernel 6: fused slice-merge + gather ----
__global__ __launch_bounds__(256) void gather_kernel(const float* __restrict__ w,
    const int* __restrict__ final_idx, const float* __restrict__ p2v,
    const int* __restrict__ p2c, float* __restrict__ out) {
  const int lane = threadIdx.x & 63;
  const int n = blockIdx.x * 4 + (threadIdx.x >> 6);
  int f = final_idx[n];
  if (f & UFLAG) {
    const int s = f & 0x3FFF;
    const int sl = lane & 31;
    float v = p2v[(size_t)sl * NTOK + s];
    int c = p2c[(size_t)sl * NTOK + s];
#pragma unroll
    for (int off = 1; off < 32; off <<= 1) {
      const float ov = __shfl_xor(v, off);
      const int oc = __shfl_xor(c, off);
      if (ov > v || (ov == v && oc < c)) { v = ov; c = oc; }
    }
    f = c;  // uniform across each 32-lane half (both halves identical)
  }
  ((float4*)(out + (size_t)n * DIM))[lane] = ((const float4*)(w + (size_t)f * DIM))[lane];
}

extern "C" void kernel_launch(void* const* d_in, const int* in_sizes, int n_in,
                              void* d_out, int out_size, void* d_ws, size_t ws_size,
                              hipStream_t stream) {
  const float* x = (const float*)d_in[0];
  const float* w = (const float*)d_in[1];
  float* out = (float*)d_out;

  char* ws = (char*)d_ws;   // ~39.5 MB used
  unsigned short* x0n = (unsigned short*)(ws);             // 8388608
  unsigned short* w0 = (unsigned short*)(ws + 8388608);    // 4194304 (tiled)
  unsigned short* w1 = (unsigned short*)(ws + 12582912);   // 4194304 (tiled)
  float* wn2 = (float*)(ws + 16777216);                    // 32768
  float* wnf = (float*)(ws + 16809984);                    // 32768
  float* pv1 = (float*)(ws + 16842752);                    // 524288
  int*   pc1 = (int*)  (ws + 17367040);                    // 524288
  float* pv2 = (float*)(ws + 17891328);                    // 524288
  int* final_idx = (int*)(ws + 18415616);                  // 65536
  int* ucount = (int*)(ws + 18481152);                     // 256
  unsigned short* xgh = (unsigned short*)(ws + 18546944);  // 8388608
  unsigned short* xgl = (unsigned short*)(ws + 26935552);  // 8388608
  float* p2v = (float*)(ws + 35324160);                    // 2097152
  int*   p2c = (int*)  (ws + 37421312);                    // 2097152

  prep_kernel<<<3072, 256, 0, stream>>>(x, w, x0n, w0, w1, wn2, wnf, ucount);
  phase1_kernel<<<64 * NCBG, 512, 0, stream>>>(x0n, w0, wn2, pv1, pc1, pv2);
  reduce_kernel<<<NTOK / 256, 256, 0, stream>>>(pv1, pc1, pv2, x, x0n,
                                                final_idx, ucount, xgh, xgl);
  rescore_kernel<<<32 * 32, 256, 0, stream>>>(xgh, xgl, w0, w1, wnf, ucount, p2v, p2c);
  gather_kernel<<<NTOK / 4, 256, 0, stream>>>(w, final_idx, p2v, p2c, out);
}

// Round 16
// 183.288 us; speedup vs baseline: 1.0413x; 1.0413x over previous
//
#include <hip/hip_runtime.h>
#include <cstddef>
#include <cstdint>

#define DIM   256
#define KCODE 8192
#define NTOK  16384
#define NCBG  8          // phase1 code groups of 1024
#define HMARGIN 0.25f    // phase1 works in half-units (0.5*wn - dot)
#define UFLAG 0x40000000

typedef __attribute__((ext_vector_type(8))) short short8;
typedef __attribute__((ext_vector_type(8))) unsigned short ushort8;
typedef __attribute__((ext_vector_type(4))) unsigned short ushort4v;
typedef __attribute__((ext_vector_type(4))) float floatx4;

__device__ __forceinline__ unsigned short f2bf(float f) {  // RNE float->bf16
  uint32_t u = __builtin_bit_cast(uint32_t, f);
  return (unsigned short)((u + 0x7fffu + ((u >> 16) & 1u)) >> 16);
}
__device__ __forceinline__ float bf2f(unsigned short h) {
  return __builtin_bit_cast(float, (uint32_t)h << 16);
}

typedef const __attribute__((address_space(1))) unsigned int guint_t;
typedef __attribute__((address_space(3))) unsigned int luint_t;
__device__ __forceinline__ void gload_lds16(const void* g, void* l) {
  __builtin_amdgcn_global_load_lds((guint_t*)g, (luint_t*)l, 16, 0, 0);
}

// ---- TILED w0/w1 global layout (verified bit-exact since R3) ----
// tile t = 32 codebook rows (16 KB). Region (kc,h) = 1024 B at (kc*2+h)*1024.
// Slot s = quad*16 + (l15^kc) (16 B) holds chunk (row h*16+l15, 16B-col kc*4+quad).
// A wave DMA of one region (base + lane*16) is contiguous 1024 B in global AND
// lands as the conflict-free k-major LDS image (reads: lane*16 ^ kc<<4).

// ---- kernel 1: bf16 split convert (x negated, w two-word TILED) + w norms ----
__global__ __launch_bounds__(256) void prep_kernel(const float* __restrict__ x,
    const float* __restrict__ w, unsigned short* __restrict__ x0n,
    unsigned short* __restrict__ w0, unsigned short* __restrict__ w1,
    float* __restrict__ wn2, float* __restrict__ wnf, int* __restrict__ ucount) {
  if (blockIdx.x == 0 && threadIdx.x == 0) *ucount = 0;
  const int lane = threadIdx.x & 63, wv = threadIdx.x >> 6;
  const int l32 = lane & 31;
  const int row = blockIdx.x * 8 + wv * 2 + (lane >> 5);
  const bool is_x = row < NTOK;
  const float* src = is_x ? (x + (size_t)row * DIM) : (w + (size_t)(row - NTOK) * DIM);
  const float4 f0 = ((const float4*)src)[l32 * 2];
  const float4 f1 = ((const float4*)src)[l32 * 2 + 1];
  const float f[8] = {f0.x, f0.y, f0.z, f0.w, f1.x, f1.y, f1.z, f1.w};
  if (is_x) {  // store bf16(-x): MFMA then accumulates (norm - dot) directly
    ushort8 o;
#pragma unroll
    for (int i = 0; i < 8; ++i) o[i] = f2bf(-f[i]);
    *(ushort8*)(x0n + (size_t)row * DIM + l32 * 8) = o;
  } else {     // two-word split: w = w0 + w1 (+ ~2^-17 residual), TILED store
    ushort8 h8, l8;
#pragma unroll
    for (int i = 0; i < 8; ++i) {
      h8[i] = f2bf(f[i]);
      l8[i] = f2bf(f[i] - bf2f(h8[i]));
    }
    const int wr = row - NTOK;
    const int kc = l32 >> 2, quad = l32 & 3;
    const size_t off = (size_t)(wr >> 5) * 8192                      // tile (shorts)
                     + (size_t)(kc * 2 + ((wr >> 4) & 1)) * 512      // region
                     + (size_t)(quad * 16 + ((wr & 15) ^ kc)) * 8;   // slot
    *(ushort8*)(w0 + off) = h8;
    *(ushort8*)(w1 + off) = l8;
    float s = f[0]*f[0] + f[1]*f[1] + f[2]*f[2] + f[3]*f[3] +
              f[4]*f[4] + f[5]*f[5] + f[6]*f[6] + f[7]*f[7];
#pragma unroll
    for (int off2 = 1; off2 < 32; off2 <<= 1) s += __shfl_xor(s, off2);
    if (l32 == 0) { wn2[wr] = 0.5f * s; wnf[wr] = s; }
  }
}

// ---- kernel 2: phase1 bf16 screen. 32 tok/wave; B via DMA ring-3. ----
// R8/R12 EXACT — the verified local optimum (82-84us, VGPR=84, conflicts=0,
// no spill). Full lever ledger: 64-tok + asm ring spills (R9, 70MB WRITE);
// setprio on this lockstep ring is negative (R13: 92.6us + spill); 8-wave
// blocks are negative (R15: 88.5us — barrier-group skew doubles, no fill
// gain); 16-way code split negative (R6); deeper rings spill (R2-R4).
__global__ __launch_bounds__(256) __attribute__((amdgpu_waves_per_eu(3, 8)))
void phase1_kernel(
    const unsigned short* __restrict__ x0n, const unsigned short* __restrict__ w0,
    const float* __restrict__ wn2,
    float* __restrict__ pv1, int* __restrict__ pc1, float* __restrict__ pv2) {
  __shared__ char smem[49152];  // ring 3 x 16KB
  const int tid = threadIdx.x;
  const int tb = blockIdx.x >> 3;    // 0..127 (128 tokens)
  const int cbg = blockIdx.x & 7;    // blockIdx%8 = XCD -> 512KB w0 slice per XCD L2
  const int lane = tid & 63, wv = tid >> 6;
  const int l15 = lane & 15, quad = lane >> 4;
  const int lane16 = lane << 4;

  // resident A FIRST in vmcnt FIFO: wave wv owns 32 tokens; af[2][8] = 64 VGPRs
  short8 af[2][8];
#pragma unroll
  for (int mt = 0; mt < 2; ++mt) {
    const unsigned short* xr =
        x0n + (size_t)(tb * 128 + wv * 32 + mt * 16 + l15) * DIM + quad * 8;
#pragma unroll
    for (int kc = 0; kc < 8; ++kc) af[mt][kc] = *(const short8*)(xr + kc * 32);
  }

  // DMA sources: wave wv stages regions rho = wv*4+j; contiguous 1024B each.
  const char* wb = (const char*)w0 + (size_t)cbg * 32 * 16384;  // 512KB slice
  const char* g0 = wb + (wv * 4 + 0) * 1024 + lane16;
  const char* g1 = wb + (wv * 4 + 1) * 1024 + lane16;
  const char* g2 = wb + (wv * 4 + 2) * 1024 + lane16;
  const char* g3 = wb + (wv * 4 + 3) * 1024 + lane16;

  float bv1[8], bv2[8];
  int bc1[8];
#pragma unroll
  for (int i = 0; i < 8; ++i) { bv1[i] = -3.4e38f; bv2[i] = -3.4e38f; bc1[i] = 0; }

#define P1_DMA(BUFOFF) { \
    gload_lds16(g0, smem + (BUFOFF) + (wv * 4 + 0) * 1024); \
    gload_lds16(g1, smem + (BUFOFF) + (wv * 4 + 1) * 1024); \
    gload_lds16(g2, smem + (BUFOFF) + (wv * 4 + 2) * 1024); \
    gload_lds16(g3, smem + (BUFOFF) + (wv * 4 + 3) * 1024); \
    g0 += 16384; g1 += 16384; g2 += 16384; g3 += 16384; }

// counted wait: tile s landed; barrier: all waves' portions landed AND all
// waves are past compute(s-1); fence: nothing sinks/hoists across.
#define P1_WAIT(N) \
    asm volatile("s_waitcnt vmcnt(" #N ")" ::: "memory"); \
    __builtin_amdgcn_s_barrier(); \
    asm volatile("" ::: "memory");

#define P1_COMPUTE(BUF, LOADN) { \
    const float cw0 = nw0, cw1 = nw1; \
    wnp += 32; \
    if (LOADN) { nw0 = wnp[0]; nw1 = wnp[16]; } \
    floatx4 acc[2][2]; \
    _Pragma("unroll") \
    for (int mt = 0; mt < 2; ++mt) { \
      acc[mt][0] = (floatx4){cw0, cw0, cw0, cw0}; \
      acc[mt][1] = (floatx4){cw1, cw1, cw1, cw1}; \
    } \
    _Pragma("unroll") \
    for (int kc = 0; kc < 8; ++kc) { \
      const int ra = lane16 ^ (kc << 4); \
      const short8 b0 = *(const short8*)(smem + (BUF) + kc * 2048 + ra); \
      const short8 b1 = *(const short8*)(smem + (BUF) + kc * 2048 + 1024 + ra); \
      _Pragma("unroll") \
      for (int mt = 0; mt < 2; ++mt) { \
        acc[mt][0] = __builtin_amdgcn_mfma_f32_16x16x32_bf16(af[mt][kc], b0, acc[mt][0], 0, 0, 0); \
        acc[mt][1] = __builtin_amdgcn_mfma_f32_16x16x32_bf16(af[mt][kc], b1, acc[mt][1], 0, 0, 0); \
      } \
    } \
    _Pragma("unroll") \
    for (int mt = 0; mt < 2; ++mt) { \
      _Pragma("unroll") \
      for (int reg = 0; reg < 4; ++reg) { \
        const int cell = mt * 4 + reg; \
        const float c0 = acc[mt][0][reg], c1 = acc[mt][1][reg]; \
        const float hi = fmaxf(c0, c1), lo = fminf(c0, c1); \
        const int ch = (c1 > c0) ? (code0 + 16) : code0;  /* tie -> lower code */ \
        const float t = fminf(bv1[cell], hi); \
        bc1[cell] = (hi > bv1[cell]) ? ch : bc1[cell];    /* tie -> earlier */ \
        bv1[cell] = fmaxf(bv1[cell], hi); \
        bv2[cell] = fmaxf(fmaxf(bv2[cell], t), lo);       /* v_max3_f32 */ \
      } \
    } \
    code0 += 32; }

  P1_DMA(0)       // tile 0 -> buf0
  P1_DMA(16384)   // tile 1 -> buf1
  const float* wnp = wn2 + cbg * 1024 + l15;
  float nw0 = wnp[0], nw1 = wnp[16];   // wn(0): 2 VMEM, newest in FIFO
  int code0 = cbg * 1024 + l15;

  // subs 0..29 (uniform: WAIT(6), issue tile s+2, compute s), 3-unrolled.
#pragma unroll 1
  for (int s3 = 0; s3 < 10; ++s3) {
    P1_WAIT(6) P1_DMA(32768) P1_COMPUTE(0, 1)       // s=3k:   buf0, issue->buf2
    P1_WAIT(6) P1_DMA(0)     P1_COMPUTE(16384, 1)   // s=3k+1: buf1, issue->buf0
    P1_WAIT(6) P1_DMA(16384) P1_COMPUTE(32768, 1)   // s=3k+2: buf2, issue->buf1
  }
  P1_WAIT(6) P1_COMPUTE(0, 1)       // s=30: buf0 (tile 30), prefetch wn(31)
  P1_WAIT(2) P1_COMPUTE(16384, 0)   // s=31: buf1 (tile 31); wn(31) is newest 2
#undef P1_DMA
#undef P1_WAIT
#undef P1_COMPUTE

  // epilogue: the 16 per-token candidates live in lanes quad*16+l15 of THIS
  // wave -> 16-lane xor-butterfly top-2 merge, no LDS, no barriers.
  // Ties: V2 ends == V1 -> gap 0 -> rescore; lane 0 keeps lowest tying code.
#pragma unroll
  for (int mt = 0; mt < 2; ++mt)
#pragma unroll
    for (int reg = 0; reg < 4; ++reg) {
      const int cell = mt * 4 + reg;
      float V1 = bv1[cell], V2 = bv2[cell];
      int C1 = bc1[cell];
#pragma unroll
      for (int off = 1; off < 16; off <<= 1) {
        const float ov1 = __shfl_xor(V1, off);
        const float ov2 = __shfl_xor(V2, off);
        const int   oc1 = __shfl_xor(C1, off);
        const bool take = ov1 > V1;
        V2 = fmaxf(fminf(V1, ov1), take ? ov2 : V2);
        V1 = take ? ov1 : V1;
        C1 = take ? oc1 : C1;
      }
      if (l15 == 0) {
        const int tok = wv * 32 + mt * 16 + quad * 4 + reg;  // C/D: row=quad*4+reg
        const size_t o = (size_t)cbg * NTOK + tb * 128 + tok;
        pv1[o] = V1; pc1[o] = C1; pv2[o] = V2;
      }
    }
}

// ---- kernel 3: FUSED merge + uncertain-compact-gather ----
// Per block: merge 8 group partials for 256 tokens; uncertain tokens get a
// global slot p (atomicAdd) and are recorded in LDS; then the block's 4 waves
// cooperatively write the compact two-word rows (same math as old xgather,
// bit-exact). Pad rows [uc, ucp) are NOT zeroed: rescore's s<uc guard discards
// every output that could depend on them.
__global__ __launch_bounds__(256) void reduce_kernel(
    const float* __restrict__ pv1, const int* __restrict__ pc1,
    const float* __restrict__ pv2, const float* __restrict__ x,
    const unsigned short* __restrict__ x0n, int* __restrict__ final_idx,
    int* __restrict__ ucount, unsigned short* __restrict__ xgh,
    unsigned short* __restrict__ xgl) {
  __shared__ int ltok[256], lslot[256];
  __shared__ int lcnt;
  const int tid = threadIdx.x;
  if (tid == 0) lcnt = 0;
  __syncthreads();
  const int n = blockIdx.x * 256 + tid;
  float V1 = -3.4e38f, V2 = -3.4e38f;
  int C1 = 0;
#pragma unroll
  for (int cb = 0; cb < NCBG; ++cb) {
    const size_t o = (size_t)cb * NTOK + n;
    const float v1 = pv1[o], v2 = pv2[o];
    const int c1 = pc1[o];
    if (v1 > V1) { V2 = fmaxf(V1, v2); V1 = v1; C1 = c1; }
    else V2 = fmaxf(V2, v1);
  }
  if (V1 - V2 < HMARGIN) {
    const int p = atomicAdd(ucount, 1);
    const int li = atomicAdd(&lcnt, 1);
    ltok[li] = n; lslot[li] = p;
    final_idx[n] = UFLAG | p;   // gather resolves via p2 slot p
  } else {
    final_idx[n] = C1;
  }
  __syncthreads();
  const int cnt = lcnt;
  const int wv = tid >> 6, lane = tid & 63;
  for (int i = wv; i < cnt; i += 4) {   // wave-per-uncertain-row
    const int tok = ltok[i], s = lslot[i];
    const ushort4v h = ((const ushort4v*)(x0n + (size_t)tok * DIM))[lane];
    const float4 f = ((const float4*)(x + (size_t)tok * DIM))[lane];
    ushort4v l;
    l[0] = f2bf(-f.x - bf2f(h[0]));
    l[1] = f2bf(-f.y - bf2f(h[1]));
    l[2] = f2bf(-f.z - bf2f(h[2]));
    l[3] = f2bf(-f.w - bf2f(h[3]));
    ((ushort4v*)(xgh + (size_t)s * DIM))[lane] = h;
    ((ushort4v*)(xgl + (size_t)s * DIM))[lane] = l;
  }
}

// ---- kernel 5: rescore v2 -- 128 slots/block, LDS-staged B (4x dedup) ----
// block = 4 waves x 32 slots = 128 slots; slice = 256 codes; grid 32x32.
// Per sub (32 codes): stage w0-tile + w1-tile (32KB) ONCE via global_load_lds
// (tiled layout: contiguous regions, conflict-free lane16^kc reads), all 4
// waves consume it -> per-slot B L2-traffic drops 4x vs R11. 2x32KB dbuf,
// one __syncthreads per sub (128 MFMA hides the DMA; R7-proven scheme).
// NO setprio (R13: negative on lockstep structures).
// Epilogue: codes live in l15 lanes of the owning wave -> in-wave 16-lane
// butterfly (max v, tie -> lower code; same total order as R11), no LDS.
// Per-(slot,code) FMA chain order identical to R11 -> bit-exact outputs.
__global__ __launch_bounds__(256) __attribute__((amdgpu_waves_per_eu(2, 8)))
void rescore_kernel(
    const unsigned short* __restrict__ xgh, const unsigned short* __restrict__ xgl,
    const unsigned short* __restrict__ w0, const unsigned short* __restrict__ w1,
    const float* __restrict__ wnf, const int* __restrict__ ucount,
    float* __restrict__ p2v, int* __restrict__ p2c) {
  const int uc = *ucount;
  if (uc == 0) return;
  const int ucp = (uc + 127) & ~127;
  const int sl = blockIdx.x & 31, g0 = blockIdx.x >> 5;  // g0 in [0,32)
  __shared__ char smem[65536];  // 2 x (w0-tile 16K | w1-tile 16K)
  const int tid = threadIdx.x;
  const int lane = tid & 63, wv = tid >> 6;
  const int l15 = lane & 15, quad = lane >> 4;
  const int lane16 = lane << 4;

  // DMA geometry: wave wv stages regions wv*8+j (j<8) of the 32KB sub-buffer:
  // wv 0,1 -> w0 tile regions 0-7 / 8-15; wv 2,3 -> w1 tile same. Source is
  // contiguous (tiled layout); dst is wave-uniform (gload_lds adds lane*16).
  const char* wsel = (wv < 2) ? (const char*)w0 : (const char*)w1;
  const char* wbase = wsel + (size_t)sl * 8 * 16384 + (size_t)(wv & 1) * 8192 + lane16;
  const int dstb = wv * 8192;

#define RS_DMA(BUF, SUB) { \
    _Pragma("unroll") \
    for (int j = 0; j < 8; ++j) \
      gload_lds16(wbase + (size_t)(SUB) * 16384 + j * 1024, \
                  smem + (BUF) + dstb + j * 1024); }

  for (int g = g0; g * 128 < ucp; g += 32) {
    RS_DMA(0, 0)   // sub 0 -> buf0 (lands under the A-loads below)

    short8 ah[2][8], al[2][8];  // 128 VGPRs
#pragma unroll
    for (int mt = 0; mt < 2; ++mt) {
      const size_t rb = (size_t)(g * 128 + wv * 32 + mt * 16 + l15) * DIM + quad * 8;
#pragma unroll
      for (int kc = 0; kc < 8; ++kc) {
        ah[mt][kc] = *(const short8*)(xgh + rb + kc * 32);
        al[mt][kc] = *(const short8*)(xgl + rb + kc * 32);
      }
    }
    float bv[8];
    int bc[8];
#pragma unroll
    for (int i = 0; i < 8; ++i) { bv[i] = -3.4e38f; bc[i] = 0; }

    const float* wnp = wnf + sl * 256 + l15;
    int code0 = sl * 256 + l15;
    __syncthreads();   // sub 0 landed (compiler drains vmcnt at barrier)

#pragma unroll 1
    for (int sub = 0; sub < 8; ++sub) {
      const int buf = (sub & 1) * 32768;
      if (sub < 7) RS_DMA((buf ^ 32768), sub + 1)
      floatx4 acc[2][2];
#pragma unroll
      for (int mt = 0; mt < 2; ++mt)
#pragma unroll
        for (int h = 0; h < 2; ++h) acc[mt][h] = (floatx4){0.f, 0.f, 0.f, 0.f};
#pragma unroll
      for (int kc = 0; kc < 8; ++kc) {
        const int ra = lane16 ^ (kc << 4);
        const short8 bh0 = *(const short8*)(smem + buf + kc * 2048 + ra);
        const short8 bh1 = *(const short8*)(smem + buf + kc * 2048 + 1024 + ra);
        const short8 bl0 = *(const short8*)(smem + buf + 16384 + kc * 2048 + ra);
        const short8 bl1 = *(const short8*)(smem + buf + 16384 + kc * 2048 + 1024 + ra);
#pragma unroll
        for (int mt = 0; mt < 2; ++mt) {
          acc[mt][0] = __builtin_amdgcn_mfma_f32_16x16x32_bf16(al[mt][kc], bl0, acc[mt][0], 0, 0, 0);
          acc[mt][0] = __builtin_amdgcn_mfma_f32_16x16x32_bf16(ah[mt][kc], bl0, acc[mt][0], 0, 0, 0);
          acc[mt][0] = __builtin_amdgcn_mfma_f32_16x16x32_bf16(al[mt][kc], bh0, acc[mt][0], 0, 0, 0);
          acc[mt][0] = __builtin_amdgcn_mfma_f32_16x16x32_bf16(ah[mt][kc], bh0, acc[mt][0], 0, 0, 0);
          acc[mt][1] = __builtin_amdgcn_mfma_f32_16x16x32_bf16(al[mt][kc], bl1, acc[mt][1], 0, 0, 0);
          acc[mt][1] = __builtin_amdgcn_mfma_f32_16x16x32_bf16(ah[mt][kc], bl1, acc[mt][1], 0, 0, 0);
          acc[mt][1] = __builtin_amdgcn_mfma_f32_16x16x32_bf16(al[mt][kc], bh1, acc[mt][1], 0, 0, 0);
          acc[mt][1] = __builtin_amdgcn_mfma_f32_16x16x32_bf16(ah[mt][kc], bh1, acc[mt][1], 0, 0, 0);
        }
      }
      const float wn0 = wnp[0], wn1 = wnp[16];
      // acc = -(x.w); dist = wn + 2*acc
#pragma unroll
      for (int mt = 0; mt < 2; ++mt) {
#pragma unroll
        for (int reg = 0; reg < 4; ++reg) {
          const int cell = mt * 4 + reg;
          const float d0 = fmaf(2.0f, acc[mt][0][reg], wn0);
          const float d1 = fmaf(2.0f, acc[mt][1][reg], wn1);
          const float hi = fmaxf(d0, d1);
          const int ch = (d1 > d0) ? (code0 + 16) : code0;  // tie -> lower code
          bc[cell] = (hi > bv[cell]) ? ch : bc[cell];
          bv[cell] = fmaxf(bv[cell], hi);
        }
      }
      wnp += 32;
      code0 += 32;
      __syncthreads();   // sub+1 landed; all readers of buf done
    }

    // epilogue: in-wave butterfly over the 16 code-lanes (same total order:
    // max v, tie -> lower code). Slot = wv*32 + mt*16 + quad*4 + reg.
#pragma unroll
    for (int mt = 0; mt < 2; ++mt)
#pragma unroll
      for (int reg = 0; reg < 4; ++reg) {
        const int cell = mt * 4 + reg;
        float V = bv[cell];
        int C = bc[cell];
#pragma unroll
        for (int off = 1; off < 16; off <<= 1) {
          const float ov = __shfl_xor(V, off);
          const int oc = __shfl_xor(C, off);
          if (ov > V || (ov == V && oc < C)) { V = ov; C = oc; }
        }
        if (l15 == 0) {
          const int s = g * 128 + wv * 32 + mt * 16 + quad * 4 + reg;
          if (s < uc) {
            p2v[(size_t)sl * NTOK + s] = V;
            p2c[(size_t)sl * NTOK + s] = C;
          }
        }
      }
  }
#undef RS_DMA
}

// ---- kernel 6: fused slice-merge + gather ----
__global__ __launch_bounds__(256) void gather_kernel(const float* __restrict__ w,
    const int* __restrict__ final_idx, const float* __restrict__ p2v,
    const int* __restrict__ p2c, float* __restrict__ out) {
  const int lane = threadIdx.x & 63;
  const int n = blockIdx.x * 4 + (threadIdx.x >> 6);
  int f = final_idx[n];
  if (f & UFLAG) {
    const int s = f & 0x3FFF;
    const int sl = lane & 31;
    float v = p2v[(size_t)sl * NTOK + s];
    int c = p2c[(size_t)sl * NTOK + s];
#pragma unroll
    for (int off = 1; off < 32; off <<= 1) {
      const float ov = __shfl_xor(v, off);
      const int oc = __shfl_xor(c, off);
      if (ov > v || (ov == v && oc < c)) { v = ov; c = oc; }
    }
    f = c;  // uniform across each 32-lane half (both halves identical)
  }
  ((float4*)(out + (size_t)n * DIM))[lane] = ((const float4*)(w + (size_t)f * DIM))[lane];
}

extern "C" void kernel_launch(void* const* d_in, const int* in_sizes, int n_in,
                              void* d_out, int out_size, void* d_ws, size_t ws_size,
                              hipStream_t stream) {
  const float* x = (const float*)d_in[0];
  const float* w = (const float*)d_in[1];
  float* out = (float*)d_out;

  char* ws = (char*)d_ws;   // ~39.5 MB used
  unsigned short* x0n = (unsigned short*)(ws);             // 8388608
  unsigned short* w0 = (unsigned short*)(ws + 8388608);    // 4194304 (tiled)
  unsigned short* w1 = (unsigned short*)(ws + 12582912);   // 4194304 (tiled)
  float* wn2 = (float*)(ws + 16777216);                    // 32768
  float* wnf = (float*)(ws + 16809984);                    // 32768
  float* pv1 = (float*)(ws + 16842752);                    // 524288
  int*   pc1 = (int*)  (ws + 17367040);                    // 524288
  float* pv2 = (float*)(ws + 17891328);                    // 524288
  int* final_idx = (int*)(ws + 18415616);                  // 65536
  int* ucount = (int*)(ws + 18481152);                     // 256
  unsigned short* xgh = (unsigned short*)(ws + 18546944);  // 8388608
  unsigned short* xgl = (unsigned short*)(ws + 26935552);  // 8388608
  float* p2v = (float*)(ws + 35324160);                    // 2097152
  int*   p2c = (int*)  (ws + 37421312);                    // 2097152

  prep_kernel<<<3072, 256, 0, stream>>>(x, w, x0n, w0, w1, wn2, wnf, ucount);
  phase1_kernel<<<128 * NCBG, 256, 0, stream>>>(x0n, w0, wn2, pv1, pc1, pv2);
  reduce_kernel<<<NTOK / 256, 256, 0, stream>>>(pv1, pc1, pv2, x, x0n,
                                                final_idx, ucount, xgh, xgl);
  rescore_kernel<<<32 * 32, 256, 0, stream>>>(xgh, xgl, w0, w1, wnf, ucount, p2v, p2c);
  gather_kernel<<<NTOK / 4, 256, 0, stream>>>(w, final_idx, p2v, p2c, out);
}